// Round 20
// baseline (346.147 us; speedup 1.0000x reference)
//
#include <hip/hip_runtime.h>
#include <hip/hip_bf16.h>

#define BB 4096
#define DD 64
#define HH 512

typedef __hip_bfloat16 bf16;
typedef _Float16 f16;
typedef __attribute__((ext_vector_type(8))) short bf16x8;
typedef __attribute__((ext_vector_type(8))) _Float16 f16x8;
typedef __attribute__((ext_vector_type(4))) float f32x4;

__device__ __forceinline__ float bf2f(bf16 x) { return __bfloat162float(x); }
__device__ __forceinline__ float u16tof(unsigned short u) {
  union { unsigned int i; float f; } v; v.i = ((unsigned int)u) << 16; return v.f;
}
#define BC8(p) __builtin_bit_cast(bf16x8, *(const uint4*)(p))
#define BCH8(p) __builtin_bit_cast(f16x8, *(const uint4*)(p))

// ws: Xbf | Ybf (B*H bf16) | W2bf | V2bf (H*H bf16, fwd) |
//     W1bf | V1bf | W3bf | V3bf (fwd; W3bf also k4-epilogue) |
//     W1Th (64x512 f16, k4) | W2h (H*H f16, k4) | Jpart (4 x B x 64 f32)
// fwd writes mu -> out[:, :64] and Qd -> out[:, 64:]; combine RMWs out[:, 64:].

// ---------------------------------------------------------------------------
// cvt: [0,256) W2bf; [256,512) V2bf; [512,544) W1Th[d*512+k]=f16(W1[k*64+d]);
//      [544,672) natural bf16 W1,V1,W3,V3; [672,928) W2h = f16(W2).
// ---------------------------------------------------------------------------
__global__ __launch_bounds__(256) void cvt_weights(
    const float* __restrict__ W2, const float* __restrict__ V2,
    const float* __restrict__ W1, const float* __restrict__ V1,
    const float* __restrict__ W3, const float* __restrict__ V3,
    bf16* __restrict__ W2bf, bf16* __restrict__ V2bf, f16* __restrict__ W1Th,
    bf16* __restrict__ W1bf, bf16* __restrict__ V1bf,
    bf16* __restrict__ W3bf, bf16* __restrict__ V3bf, f16* __restrict__ W2h) {
  int blk = blockIdx.x, t = threadIdx.x;
  if (blk < 512) {
    const float* src = (blk < 256) ? W2 : V2;
    bf16* dst = (blk < 256) ? W2bf : V2bf;
    int i = ((blk & 255) * 256 + t) * 4;
    float4 v = *(const float4*)(src + i);
    bf16 o[4] = {__float2bfloat16(v.x), __float2bfloat16(v.y),
                 __float2bfloat16(v.z), __float2bfloat16(v.w)};
    *(uint2*)(dst + i) = *(uint2*)o;
  } else if (blk < 544) {
    int e = (blk - 512) * 1024 + t * 4;
    int d = e >> 9, k0 = e & 511;
    f16 o[4];
#pragma unroll
    for (int j = 0; j < 4; ++j) o[j] = (f16)W1[(size_t)(k0 + j) * 64 + d];
    *(uint2*)(W1Th + e) = *(uint2*)o;
  } else if (blk < 672) {
    int which = (blk - 544) >> 5;
    int local = (blk - 544) & 31;
    const float* src = (which == 0) ? W1 : (which == 1) ? V1 : (which == 2) ? W3 : V3;
    bf16* dst = (which == 0) ? W1bf : (which == 1) ? V1bf : (which == 2) ? W3bf : V3bf;
    int i = (local * 256 + t) * 4;
    float4 v = *(const float4*)(src + i);
    bf16 o[4] = {__float2bfloat16(v.x), __float2bfloat16(v.y),
                 __float2bfloat16(v.z), __float2bfloat16(v.w)};
    *(uint2*)(dst + i) = *(uint2*)o;
  } else {
    int i = ((blk - 672) * 256 + t) * 4;
    float4 v = *(const float4*)(W2 + i);
    f16 o[4] = {(f16)v.x, (f16)v.y, (f16)v.z, (f16)v.w};
    *(uint2*)(W2h + i) = *(uint2*)o;
  }
}

// ---------------------------------------------------------------------------
// fwd v2 (R19 verbatim): 32-row stripes, grid (128, 2), 2 blocks/CU.
// ---------------------------------------------------------------------------
__global__ __launch_bounds__(256) void fwd(
    const float* __restrict__ states,
    const bf16* __restrict__ W1bf, const float* __restrict__ b1,
    const bf16* __restrict__ W2bf, const float* __restrict__ b2,
    const bf16* __restrict__ W3bf, const float* __restrict__ b3,
    const bf16* __restrict__ V1bf, const float* __restrict__ c1,
    const bf16* __restrict__ V2bf, const float* __restrict__ c2,
    const bf16* __restrict__ V3bf, const float* __restrict__ c3,
    bf16* __restrict__ Xbf, bf16* __restrict__ Ybf, float* __restrict__ out) {
  __shared__ __align__(16) bf16 mus[32 * 72];
  __shared__ __align__(16) bf16 Xres[32 * 520];
  __shared__ __align__(16) bf16 Bs[128 * 72];
  __shared__ __align__(16) bf16 Ych[32 * 136];
  const int bt = blockIdx.x * 32;
  const int path = blockIdx.y;
  const bf16* Wa = path ? V1bf : W1bf;
  const float* ba = path ? c1 : b1;
  const bf16* Wb = path ? V2bf : W2bf;
  const float* bbv = path ? c2 : b2;
  const bf16* Wc = path ? V3bf : W3bf;
  const float* bcv = path ? c3 : b3;
  const int t = threadIdx.x;
  const int lane = t & 63;
  const int w = t >> 6;
  const int c = lane & 15, q = lane >> 4;

  {
    int row = t >> 3, cg = (t & 7) * 8;
    bf16 o[8];
#pragma unroll
    for (int j = 0; j < 8; j += 4) {
      float4 v = *(const float4*)(states + (size_t)(bt + row) * 128 + cg + j);
      o[j] = __float2bfloat16(v.x); o[j + 1] = __float2bfloat16(v.y);
      o[j + 2] = __float2bfloat16(v.z); o[j + 3] = __float2bfloat16(v.w);
    }
    *(uint4*)(mus + row * 72 + cg) = *(const uint4*)o;
  }
  __syncthreads();

  // L1: X = tanh(mu @ Wa^T + ba), K=64, 4 N-chunks of 128
  for (int nch = 0; nch < 4; ++nch) {
    if (nch) __syncthreads();
#pragma unroll
    for (int i = 0; i < 4; ++i) {
      int g = t + i * 256;
      int row = g >> 3, kb = (g & 7) * 8;
      *(uint4*)(Bs + row * 72 + kb) =
          *(const uint4*)(Wa + (size_t)(nch * 128 + row) * 64 + kb);
    }
    __syncthreads();
    f32x4 acc1[2][2] = {};
#pragma unroll
    for (int s = 0; s < 2; ++s) {
      bf16x8 af[2], bfr[2];
#pragma unroll
      for (int mt = 0; mt < 2; ++mt)
        af[mt] = BC8(mus + (mt * 16 + c) * 72 + s * 32 + q * 8);
#pragma unroll
      for (int nt = 0; nt < 2; ++nt)
        bfr[nt] = BC8(Bs + (w * 32 + nt * 16 + c) * 72 + s * 32 + q * 8);
#pragma unroll
      for (int mt = 0; mt < 2; ++mt)
#pragma unroll
        for (int nt = 0; nt < 2; ++nt)
          acc1[mt][nt] = __builtin_amdgcn_mfma_f32_16x16x32_bf16(
              af[mt], bfr[nt], acc1[mt][nt], 0, 0, 0);
    }
#pragma unroll
    for (int nt = 0; nt < 2; ++nt) {
      int col = nch * 128 + w * 32 + nt * 16 + c;
      float bias = ba[col];
#pragma unroll
      for (int mt = 0; mt < 2; ++mt)
#pragma unroll
        for (int r = 0; r < 4; ++r) {
          int row = mt * 16 + q * 4 + r;
          float x = tanhf(acc1[mt][nt][r] + bias);
          Xres[row * 520 + col] = __float2bfloat16(x);
          if (!path) Xbf[(size_t)(bt + row) * HH + col] = __float2bfloat16(x);
        }
    }
  }
  __syncthreads();

  // L2 + L3-fold over 4 h-chunks of 128
  f32x4 acc3[2] = {};
  for (int hch = 0; hch < 4; ++hch) {
    f32x4 acc2[2][2] = {};
    for (int kc = 0; kc < 8; ++kc) {
      __syncthreads();
#pragma unroll
      for (int i = 0; i < 4; ++i) {
        int g = t + i * 256;
        int row = g >> 3, kb = (g & 7) * 8;
        *(uint4*)(Bs + row * 72 + kb) =
            *(const uint4*)(Wb + (size_t)(hch * 128 + row) * HH + kc * 64 + kb);
      }
      __syncthreads();
#pragma unroll
      for (int s = 0; s < 2; ++s) {
        bf16x8 af[2], bfr[2];
#pragma unroll
        for (int mt = 0; mt < 2; ++mt)
          af[mt] = BC8(Xres + (mt * 16 + c) * 520 + kc * 64 + s * 32 + q * 8);
#pragma unroll
        for (int nt = 0; nt < 2; ++nt)
          bfr[nt] = BC8(Bs + (w * 32 + nt * 16 + c) * 72 + s * 32 + q * 8);
#pragma unroll
        for (int mt = 0; mt < 2; ++mt)
#pragma unroll
          for (int nt = 0; nt < 2; ++nt)
            acc2[mt][nt] = __builtin_amdgcn_mfma_f32_16x16x32_bf16(
                af[mt], bfr[nt], acc2[mt][nt], 0, 0, 0);
      }
    }
    __syncthreads();
#pragma unroll
    for (int nt = 0; nt < 2; ++nt) {
      int hl = w * 32 + nt * 16 + c;
      int h = hch * 128 + hl;
      float bias = bbv[h];
#pragma unroll
      for (int mt = 0; mt < 2; ++mt)
#pragma unroll
        for (int r = 0; r < 4; ++r) {
          int row = mt * 16 + q * 4 + r;
          float y = tanhf(acc2[mt][nt][r] + bias);
          Ych[row * 136 + hl] = __float2bfloat16(y);
          if (!path) Ybf[(size_t)(bt + row) * HH + h] = __float2bfloat16(y);
        }
    }
    __syncthreads();
#pragma unroll
    for (int s3 = 0; s3 < 4; ++s3) {
      bf16x8 bf3 = BC8(Wc + (size_t)(w * 16 + c) * HH + hch * 128 + s3 * 32 + q * 8);
#pragma unroll
      for (int mt = 0; mt < 2; ++mt) {
        bf16x8 af3 = BC8(Ych + (mt * 16 + c) * 136 + s3 * 32 + q * 8);
        acc3[mt] = __builtin_amdgcn_mfma_f32_16x16x32_bf16(af3, bf3, acc3[mt], 0, 0, 0);
      }
    }
  }
  {
    int o = w * 16 + c;
    float bias = bcv[o];
#pragma unroll
    for (int mt = 0; mt < 2; ++mt)
#pragma unroll
      for (int r = 0; r < 4; ++r) {
        int row = mt * 16 + q * 4 + r;
        float v = acc3[mt][r] + bias;
        if (path) {
          v = fmaxf(v, 0.0f) + log1pf(expf(-fabsf(v)));
          out[(size_t)(bt + row) * 128 + 64 + o] = v;
        } else {
          out[(size_t)(bt + row) * 128 + o] = v;
        }
      }
  }
}

// ---------------------------------------------------------------------------
// k4 v12: R17's fp16 K-loop verbatim, but w3s moved OUT of LDS — epilogue
// reads W3bf (bf16, L2-resident, coalesced 32B segments) directly. LDS
// 58.4 -> 41 KB -> 3 blocks/CU. grid (2048, 4), 128x128, BK=64.
// ---------------------------------------------------------------------------
__global__ __launch_bounds__(256) void k4_gemm(
    const bf16* __restrict__ Xbf, const bf16* __restrict__ Ybf,
    const f16* __restrict__ W1Th, const f16* __restrict__ W2h,
    const bf16* __restrict__ W3bf, float* __restrict__ Jpart) {
  __shared__ __align__(16) f16 As[128 * 72];       // 18432 B
  __shared__ __align__(16) f16 Bs[128 * 72];       // 18432 B
  __shared__ __align__(16) f16 d1h[2 * 512];       //  2048 B
  __shared__ __align__(16) float d2f[2 * 128];     //  1024 B
  __shared__ float red[256];                       //  1024 B
  const int bt = blockIdx.x;                       // b-pair index
  const int h0 = blockIdx.y * 128;
  const int t = threadIdx.x;
  const int lane = t & 63;
  const int w = t >> 6, wm = w & 1, wn = w >> 1;
  const int c = lane & 15, q = lane >> 4;

  // stage d1h = f16(1 - h1^2) (2 rows x 512)
#pragma unroll
  for (int i = 0; i < 4; ++i) {
    int e = t + i * 256;
    float x = bf2f(Xbf[(size_t)(bt * 2 + (e >> 9)) * HH + (e & 511)]);
    d1h[e] = (f16)(1.0f - x * x);
  }
  // stage d2f = 1 - h2^2 for this h-tile (2 x 128, f32)
  {
    float y = bf2f(Ybf[(size_t)(bt * 2 + (t >> 7)) * HH + h0 + (t & 127)]);
    d2f[t] = 1.0f - y * y;
  }
  __syncthreads();

  f32x4 acc[4][4] = {};
  for (int kc = 0; kc < 8; ++kc) {
    // build As via packed f16 mul + copy Bs
#pragma unroll
    for (int i = 0; i < 4; ++i) {
      int g = t + i * 256;
      int m = g >> 3, kb = (g & 7) * 8;
      int bb = m >> 6, dl = m & 63;
      f16x8 w1v = BCH8(W1Th + (size_t)dl * HH + kc * 64 + kb);
      f16x8 d1v = BCH8(d1h + bb * 512 + kc * 64 + kb);
      f16x8 av = d1v * w1v;                         // 4x v_pk_mul_f16
      *(uint4*)(As + m * 72 + kb) = __builtin_bit_cast(uint4, av);
      *(uint4*)(Bs + m * 72 + kb) =
          *(const uint4*)(W2h + (size_t)(h0 + m) * HH + kc * 64 + kb);
    }
    __syncthreads();
#pragma unroll
    for (int s = 0; s < 2; ++s) {
      f16x8 af[4], bfr[4];
#pragma unroll
      for (int mt = 0; mt < 4; ++mt)
        af[mt] = BCH8(As + (wm * 64 + mt * 16 + c) * 72 + s * 32 + q * 8);
#pragma unroll
      for (int nt = 0; nt < 4; ++nt)
        bfr[nt] = BCH8(Bs + (wn * 64 + nt * 16 + c) * 72 + s * 32 + q * 8);
#pragma unroll
      for (int mt = 0; mt < 4; ++mt)
#pragma unroll
        for (int nt = 0; nt < 4; ++nt)
          acc[mt][nt] = __builtin_amdgcn_mfma_f32_16x16x32_f16(
              af[mt], bfr[nt], acc[mt][nt], 0, 0, 0);
    }
    __syncthreads();
  }

  // epilogue: v[m] = sum_n C[m,n] * d2f[bb,n] * W3bf[dl, h0+n]; reduce lanes
#pragma unroll
  for (int mt = 0; mt < 4; ++mt) {
#pragma unroll
    for (int r = 0; r < 4; ++r) {
      int m = wm * 64 + mt * 16 + q * 4 + r;
      int bb = m >> 6, dl = m & 63;
      float v = 0.f;
#pragma unroll
      for (int nt = 0; nt < 4; ++nt) {
        int n = wn * 64 + nt * 16 + c;
        float w3 = bf2f(W3bf[(size_t)dl * HH + h0 + n]);
        v += acc[mt][nt][r] * d2f[bb * 128 + n] * w3;
      }
      v += __shfl_xor(v, 1);
      v += __shfl_xor(v, 2);
      v += __shfl_xor(v, 4);
      v += __shfl_xor(v, 8);
      if (c == 0) red[wn * 128 + m] = v;
    }
  }
  __syncthreads();
  if (t < 128) {
    float J = red[t] + red[128 + t];
    Jpart[(size_t)blockIdx.y * (BB * 64) + (size_t)bt * 128 + t] = J;
  }
}

// ---------------------------------------------------------------------------
// combine: out[b,64+d] = 2*(sum of 4 Jpart planes)*sigma + out (Qd stash)
// ---------------------------------------------------------------------------
__global__ __launch_bounds__(256) void combine(
    const float* __restrict__ Jpart, const float* __restrict__ states,
    float* __restrict__ out) {
  int idx = blockIdx.x * 256 + threadIdx.x;
  int b = idx >> 6, d = idx & 63;
  const int plane = BB * 64;
  float J = Jpart[idx] + Jpart[plane + idx] + Jpart[2 * plane + idx] +
            Jpart[3 * plane + idx];
  float sig = states[(size_t)b * 128 + 64 + d];
  float qd = out[(size_t)b * 128 + 64 + d];
  out[(size_t)b * 128 + 64 + d] = 2.0f * J * sig + qd;
}

extern "C" void kernel_launch(void* const* d_in, const int* in_sizes, int n_in,
                              void* d_out, int out_size, void* d_ws, size_t ws_size,
                              hipStream_t stream) {
  // inputs: 0:t 1:states 2:W1 3:b1 4:W2 5:b2 6:W3 7:b3 8:V1 9:c1 10:V2 11:c2 12:V3 13:c3
  const float* states = (const float*)d_in[1];
  const float* W1 = (const float*)d_in[2];
  const float* b1 = (const float*)d_in[3];
  const float* W2 = (const float*)d_in[4];
  const float* b2 = (const float*)d_in[5];
  const float* W3 = (const float*)d_in[6];
  const float* b3 = (const float*)d_in[7];
  const float* V1 = (const float*)d_in[8];
  const float* c1 = (const float*)d_in[9];
  const float* V2 = (const float*)d_in[10];
  const float* c2 = (const float*)d_in[11];
  const float* V3 = (const float*)d_in[12];
  const float* c3 = (const float*)d_in[13];
  float* out = (float*)d_out;

  bf16* Xbf = (bf16*)d_ws;                         // B*H  (4 MB)
  bf16* Ybf = Xbf + (size_t)BB * HH;               // B*H  (4 MB)
  bf16* W2bf = Ybf + (size_t)BB * HH;              // H*H  (0.5 MB)
  bf16* V2bf = W2bf + (size_t)HH * HH;             // H*H  (0.5 MB)
  bf16* W1bf = V2bf + (size_t)HH * HH;             // 512x64
  bf16* V1bf = W1bf + (size_t)HH * DD;             // 512x64
  bf16* W3bf = V1bf + (size_t)HH * DD;             // 64x512
  bf16* V3bf = W3bf + (size_t)DD * HH;             // 64x512
  f16* W1Th = (f16*)(V3bf + (size_t)DD * HH);      // 64x512 f16
  f16* W2h = W1Th + (size_t)DD * HH;               // H*H f16 (0.5 MB)
  float* Jpart = (float*)(W2h + (size_t)HH * HH);  // 4*B*64 f32 (4 MB)

  cvt_weights<<<dim3(928), 256, 0, stream>>>(W2, V2, W1, V1, W3, V3,
                                             W2bf, V2bf, W1Th, W1bf, V1bf,
                                             W3bf, V3bf, W2h);
  fwd<<<dim3(128, 2), 256, 0, stream>>>(states, W1bf, b1, W2bf, b2, W3bf, b3,
                                        V1bf, c1, V2bf, c2, V3bf, c3,
                                        Xbf, Ybf, out);
  k4_gemm<<<dim3(2048, 4), 256, 0, stream>>>(Xbf, Ybf, W1Th, W2h, W3bf, Jpart);
  combine<<<dim3(1024), 256, 0, stream>>>(Jpart, states, out);
}

// Round 21
// 321.838 us; speedup vs baseline: 1.0755x; 1.0755x over previous
//
#include <hip/hip_runtime.h>
#include <hip/hip_bf16.h>

#define BB 4096
#define DD 64
#define HH 512

typedef __hip_bfloat16 bf16;
typedef _Float16 f16;
typedef __attribute__((ext_vector_type(8))) short bf16x8;
typedef __attribute__((ext_vector_type(8))) _Float16 f16x8;
typedef __attribute__((ext_vector_type(4))) float f32x4;

__device__ __forceinline__ float bf2f(bf16 x) { return __bfloat162float(x); }
__device__ __forceinline__ float u16tof(unsigned short u) {
  union { unsigned int i; float f; } v; v.i = ((unsigned int)u) << 16; return v.f;
}
#define BC8(p) __builtin_bit_cast(bf16x8, *(const uint4*)(p))
#define BCH8(p) __builtin_bit_cast(f16x8, *(const uint4*)(p))

// ws: Xbf | Ybf (B*H bf16) | W2bf | V2bf (H*H bf16, fwd) |
//     W1bf | V1bf | W3bf | V3bf (fwd) | W1Th (64x512 f16, k4) |
//     W2h (H*H f16, k4) | Jpart (4 x B x 64 f32)   ~13.9 MB
// fwd writes mu -> out[:, :64] and Qd -> out[:, 64:]; combine RMWs out[:, 64:].

// ---------------------------------------------------------------------------
// cvt: [0,256) W2bf; [256,512) V2bf; [512,544) W1Th[d*512+k]=f16(W1[k*64+d]);
//      [544,672) natural bf16 W1,V1,W3,V3; [672,928) W2h = f16(W2).
// ---------------------------------------------------------------------------
__global__ __launch_bounds__(256) void cvt_weights(
    const float* __restrict__ W2, const float* __restrict__ V2,
    const float* __restrict__ W1, const float* __restrict__ V1,
    const float* __restrict__ W3, const float* __restrict__ V3,
    bf16* __restrict__ W2bf, bf16* __restrict__ V2bf, f16* __restrict__ W1Th,
    bf16* __restrict__ W1bf, bf16* __restrict__ V1bf,
    bf16* __restrict__ W3bf, bf16* __restrict__ V3bf, f16* __restrict__ W2h) {
  int blk = blockIdx.x, t = threadIdx.x;
  if (blk < 512) {
    const float* src = (blk < 256) ? W2 : V2;
    bf16* dst = (blk < 256) ? W2bf : V2bf;
    int i = ((blk & 255) * 256 + t) * 4;
    float4 v = *(const float4*)(src + i);
    bf16 o[4] = {__float2bfloat16(v.x), __float2bfloat16(v.y),
                 __float2bfloat16(v.z), __float2bfloat16(v.w)};
    *(uint2*)(dst + i) = *(uint2*)o;
  } else if (blk < 544) {
    int e = (blk - 512) * 1024 + t * 4;
    int d = e >> 9, k0 = e & 511;
    f16 o[4];
#pragma unroll
    for (int j = 0; j < 4; ++j) o[j] = (f16)W1[(size_t)(k0 + j) * 64 + d];
    *(uint2*)(W1Th + e) = *(uint2*)o;
  } else if (blk < 672) {
    int which = (blk - 544) >> 5;
    int local = (blk - 544) & 31;
    const float* src = (which == 0) ? W1 : (which == 1) ? V1 : (which == 2) ? W3 : V3;
    bf16* dst = (which == 0) ? W1bf : (which == 1) ? V1bf : (which == 2) ? W3bf : V3bf;
    int i = (local * 256 + t) * 4;
    float4 v = *(const float4*)(src + i);
    bf16 o[4] = {__float2bfloat16(v.x), __float2bfloat16(v.y),
                 __float2bfloat16(v.z), __float2bfloat16(v.w)};
    *(uint2*)(dst + i) = *(uint2*)o;
  } else {
    int i = ((blk - 672) * 256 + t) * 4;
    float4 v = *(const float4*)(W2 + i);
    f16 o[4] = {(f16)v.x, (f16)v.y, (f16)v.z, (f16)v.w};
    *(uint2*)(W2h + i) = *(uint2*)o;
  }
}

// ---------------------------------------------------------------------------
// fwd v3: 16-row stripes -> grid (256, 2) = 512 blocks, LDS 41.7 KB (3/CU
// allowed, ~2/CU actual across the whole GPU). Same layer structure/barrier
// discipline as the verified v2; M-tile count drops to 1 (rows = q*4+r).
// ---------------------------------------------------------------------------
__global__ __launch_bounds__(256) void fwd(
    const float* __restrict__ states,
    const bf16* __restrict__ W1bf, const float* __restrict__ b1,
    const bf16* __restrict__ W2bf, const float* __restrict__ b2,
    const bf16* __restrict__ W3bf, const float* __restrict__ b3,
    const bf16* __restrict__ V1bf, const float* __restrict__ c1,
    const bf16* __restrict__ V2bf, const float* __restrict__ c2,
    const bf16* __restrict__ V3bf, const float* __restrict__ c3,
    bf16* __restrict__ Xbf, bf16* __restrict__ Ybf, float* __restrict__ out) {
  __shared__ __align__(16) bf16 mus[16 * 72];     //  2304 B
  __shared__ __align__(16) bf16 Xres[16 * 520];   // 16640 B
  __shared__ __align__(16) bf16 Bs[128 * 72];     // 18432 B
  __shared__ __align__(16) bf16 Ych[16 * 136];    //  4352 B
  const int bt = blockIdx.x * 16;
  const int path = blockIdx.y;
  const bf16* Wa = path ? V1bf : W1bf;
  const float* ba = path ? c1 : b1;
  const bf16* Wb = path ? V2bf : W2bf;
  const float* bbv = path ? c2 : b2;
  const bf16* Wc = path ? V3bf : W3bf;
  const float* bcv = path ? c3 : b3;
  const int t = threadIdx.x;
  const int lane = t & 63;
  const int w = t >> 6;
  const int c = lane & 15, q = lane >> 4;

  // stage mu (16 x 64) -> bf16, stride 72; threads t<128, 8 elems each
  if (t < 128) {
    int row = t >> 3, cg = (t & 7) * 8;
    bf16 o[8];
#pragma unroll
    for (int j = 0; j < 8; j += 4) {
      float4 v = *(const float4*)(states + (size_t)(bt + row) * 128 + cg + j);
      o[j] = __float2bfloat16(v.x); o[j + 1] = __float2bfloat16(v.y);
      o[j + 2] = __float2bfloat16(v.z); o[j + 3] = __float2bfloat16(v.w);
    }
    *(uint4*)(mus + row * 72 + cg) = *(const uint4*)o;
  }
  __syncthreads();

  // L1: X = tanh(mu @ Wa^T + ba), K=64, 4 N-chunks of 128
  for (int nch = 0; nch < 4; ++nch) {
    if (nch) __syncthreads();
#pragma unroll
    for (int i = 0; i < 4; ++i) {
      int g = t + i * 256;
      int row = g >> 3, kb = (g & 7) * 8;
      *(uint4*)(Bs + row * 72 + kb) =
          *(const uint4*)(Wa + (size_t)(nch * 128 + row) * 64 + kb);
    }
    __syncthreads();
    f32x4 acc1[2] = {};
#pragma unroll
    for (int s = 0; s < 2; ++s) {
      bf16x8 af = BC8(mus + c * 72 + s * 32 + q * 8);
#pragma unroll
      for (int nt = 0; nt < 2; ++nt) {
        bf16x8 bfr = BC8(Bs + (w * 32 + nt * 16 + c) * 72 + s * 32 + q * 8);
        acc1[nt] = __builtin_amdgcn_mfma_f32_16x16x32_bf16(af, bfr, acc1[nt], 0, 0, 0);
      }
    }
#pragma unroll
    for (int nt = 0; nt < 2; ++nt) {
      int col = nch * 128 + w * 32 + nt * 16 + c;
      float bias = ba[col];
#pragma unroll
      for (int r = 0; r < 4; ++r) {
        int row = q * 4 + r;
        float x = tanhf(acc1[nt][r] + bias);
        Xres[row * 520 + col] = __float2bfloat16(x);
        if (!path) Xbf[(size_t)(bt + row) * HH + col] = __float2bfloat16(x);
      }
    }
  }
  __syncthreads();

  // L2 + L3-fold over 4 h-chunks of 128
  f32x4 acc3 = {};
  for (int hch = 0; hch < 4; ++hch) {
    f32x4 acc2[2] = {};
    for (int kc = 0; kc < 8; ++kc) {
      __syncthreads();
#pragma unroll
      for (int i = 0; i < 4; ++i) {
        int g = t + i * 256;
        int row = g >> 3, kb = (g & 7) * 8;
        *(uint4*)(Bs + row * 72 + kb) =
            *(const uint4*)(Wb + (size_t)(hch * 128 + row) * HH + kc * 64 + kb);
      }
      __syncthreads();
#pragma unroll
      for (int s = 0; s < 2; ++s) {
        bf16x8 af = BC8(Xres + c * 520 + kc * 64 + s * 32 + q * 8);
#pragma unroll
        for (int nt = 0; nt < 2; ++nt) {
          bf16x8 bfr = BC8(Bs + (w * 32 + nt * 16 + c) * 72 + s * 32 + q * 8);
          acc2[nt] = __builtin_amdgcn_mfma_f32_16x16x32_bf16(af, bfr, acc2[nt], 0, 0, 0);
        }
      }
    }
    __syncthreads();
#pragma unroll
    for (int nt = 0; nt < 2; ++nt) {
      int hl = w * 32 + nt * 16 + c;
      int h = hch * 128 + hl;
      float bias = bbv[h];
#pragma unroll
      for (int r = 0; r < 4; ++r) {
        int row = q * 4 + r;
        float y = tanhf(acc2[nt][r] + bias);
        Ych[row * 136 + hl] = __float2bfloat16(y);
        if (!path) Ybf[(size_t)(bt + row) * HH + h] = __float2bfloat16(y);
      }
    }
    __syncthreads();
    // L3 fold over this h-chunk (K=128): wave w owns outputs w*16+c
#pragma unroll
    for (int s3 = 0; s3 < 4; ++s3) {
      bf16x8 bf3 = BC8(Wc + (size_t)(w * 16 + c) * HH + hch * 128 + s3 * 32 + q * 8);
      bf16x8 af3 = BC8(Ych + c * 136 + s3 * 32 + q * 8);
      acc3 = __builtin_amdgcn_mfma_f32_16x16x32_bf16(af3, bf3, acc3, 0, 0, 0);
    }
  }
  // L3 epilogue -> out (f32)
  {
    int o = w * 16 + c;
    float bias = bcv[o];
#pragma unroll
    for (int r = 0; r < 4; ++r) {
      int row = q * 4 + r;
      float v = acc3[r] + bias;
      if (path) {
        v = fmaxf(v, 0.0f) + log1pf(expf(-fabsf(v)));
        out[(size_t)(bt + row) * 128 + 64 + o] = v;
      } else {
        out[(size_t)(bt + row) * 128 + o] = v;
      }
    }
  }
}

// ---------------------------------------------------------------------------
// k4 v10 (R17 verbatim — plateau kernel, 237 us measured): fp16 GEMM,
// As = d1h x W1Th packed-mul build in LDS, Bs pure copy from W2h, w3s in LDS,
// mfma_f32_16x16x32_f16, 2 barriers/kc. grid (2048, 4), 128x128, BK=64.
// ---------------------------------------------------------------------------
__global__ __launch_bounds__(256) void k4_gemm(
    const bf16* __restrict__ Xbf, const bf16* __restrict__ Ybf,
    const f16* __restrict__ W1Th, const f16* __restrict__ W2h,
    const float* __restrict__ W3, float* __restrict__ Jpart) {
  __shared__ __align__(16) f16 As[128 * 72];       // 18432 B
  __shared__ __align__(16) f16 Bs[128 * 72];       // 18432 B
  __shared__ __align__(16) f16 w3s[64 * 136];      // 17408 B
  __shared__ __align__(16) f16 d1h[2 * 512];       //  2048 B
  __shared__ __align__(16) float d2f[2 * 128];     //  1024 B
  __shared__ float red[256];                       //  1024 B
  const int bt = blockIdx.x;                       // b-pair index
  const int h0 = blockIdx.y * 128;
  const int t = threadIdx.x;
  const int lane = t & 63;
  const int w = t >> 6, wm = w & 1, wn = w >> 1;
  const int c = lane & 15, q = lane >> 4;

  // stage d1h = f16(1 - h1^2) (2 rows x 512)
#pragma unroll
  for (int i = 0; i < 4; ++i) {
    int e = t + i * 256;
    float x = bf2f(Xbf[(size_t)(bt * 2 + (e >> 9)) * HH + (e & 511)]);
    d1h[e] = (f16)(1.0f - x * x);
  }
  // stage d2f = 1 - h2^2 for this h-tile (2 x 128, f32)
  {
    float y = bf2f(Ybf[(size_t)(bt * 2 + (t >> 7)) * HH + h0 + (t & 127)]);
    d2f[t] = 1.0f - y * y;
  }
  // stage w3s = f16(W3[dl, h0+hl]) (64 x 128, stride 136)
#pragma unroll
  for (int i = 0; i < 8; ++i) {
    int e = (t + i * 256) * 4;
    int dl = e >> 7, hl = e & 127;
    float4 v = *(const float4*)(W3 + (size_t)dl * HH + h0 + hl);
    f16 o[4] = {(f16)v.x, (f16)v.y, (f16)v.z, (f16)v.w};
    *(uint2*)(w3s + dl * 136 + hl) = *(uint2*)o;
  }
  __syncthreads();

  f32x4 acc[4][4] = {};
  for (int kc = 0; kc < 8; ++kc) {
    // build As via packed f16 mul + copy Bs
#pragma unroll
    for (int i = 0; i < 4; ++i) {
      int g = t + i * 256;
      int m = g >> 3, kb = (g & 7) * 8;
      int bb = m >> 6, dl = m & 63;
      f16x8 w1v = BCH8(W1Th + (size_t)dl * HH + kc * 64 + kb);
      f16x8 d1v = BCH8(d1h + bb * 512 + kc * 64 + kb);
      f16x8 av = d1v * w1v;                         // 4x v_pk_mul_f16
      *(uint4*)(As + m * 72 + kb) = __builtin_bit_cast(uint4, av);
      *(uint4*)(Bs + m * 72 + kb) =
          *(const uint4*)(W2h + (size_t)(h0 + m) * HH + kc * 64 + kb);
    }
    __syncthreads();
#pragma unroll
    for (int s = 0; s < 2; ++s) {
      f16x8 af[4], bfr[4];
#pragma unroll
      for (int mt = 0; mt < 4; ++mt)
        af[mt] = BCH8(As + (wm * 64 + mt * 16 + c) * 72 + s * 32 + q * 8);
#pragma unroll
      for (int nt = 0; nt < 4; ++nt)
        bfr[nt] = BCH8(Bs + (wn * 64 + nt * 16 + c) * 72 + s * 32 + q * 8);
#pragma unroll
      for (int mt = 0; mt < 4; ++mt)
#pragma unroll
        for (int nt = 0; nt < 4; ++nt)
          acc[mt][nt] = __builtin_amdgcn_mfma_f32_16x16x32_f16(
              af[mt], bfr[nt], acc[mt][nt], 0, 0, 0);
    }
    __syncthreads();
  }

  // epilogue: v[m] = sum_n C[m,n] * d2f[bb,n] * w3s[dl,n]; reduce over c lanes
#pragma unroll
  for (int mt = 0; mt < 4; ++mt) {
#pragma unroll
    for (int r = 0; r < 4; ++r) {
      int m = wm * 64 + mt * 16 + q * 4 + r;
      int bb = m >> 6, dl = m & 63;
      float v = 0.f;
#pragma unroll
      for (int nt = 0; nt < 4; ++nt) {
        int n = wn * 64 + nt * 16 + c;
        v += acc[mt][nt][r] * d2f[bb * 128 + n] * (float)w3s[dl * 136 + n];
      }
      v += __shfl_xor(v, 1);
      v += __shfl_xor(v, 2);
      v += __shfl_xor(v, 4);
      v += __shfl_xor(v, 8);
      if (c == 0) red[wn * 128 + m] = v;
    }
  }
  __syncthreads();
  if (t < 128) {
    float J = red[t] + red[128 + t];
    Jpart[(size_t)blockIdx.y * (BB * 64) + (size_t)bt * 128 + t] = J;
  }
}

// ---------------------------------------------------------------------------
// combine: out[b,64+d] = 2*(sum of 4 Jpart planes)*sigma + out (Qd stash)
// ---------------------------------------------------------------------------
__global__ __launch_bounds__(256) void combine(
    const float* __restrict__ Jpart, const float* __restrict__ states,
    float* __restrict__ out) {
  int idx = blockIdx.x * 256 + threadIdx.x;
  int b = idx >> 6, d = idx & 63;
  const int plane = BB * 64;
  float J = Jpart[idx] + Jpart[plane + idx] + Jpart[2 * plane + idx] +
            Jpart[3 * plane + idx];
  float sig = states[(size_t)b * 128 + 64 + d];
  float qd = out[(size_t)b * 128 + 64 + d];
  out[(size_t)b * 128 + 64 + d] = 2.0f * J * sig + qd;
}

extern "C" void kernel_launch(void* const* d_in, const int* in_sizes, int n_in,
                              void* d_out, int out_size, void* d_ws, size_t ws_size,
                              hipStream_t stream) {
  // inputs: 0:t 1:states 2:W1 3:b1 4:W2 5:b2 6:W3 7:b3 8:V1 9:c1 10:V2 11:c2 12:V3 13:c3
  const float* states = (const float*)d_in[1];
  const float* W1 = (const float*)d_in[2];
  const float* b1 = (const float*)d_in[3];
  const float* W2 = (const float*)d_in[4];
  const float* b2 = (const float*)d_in[5];
  const float* W3 = (const float*)d_in[6];
  const float* b3 = (const float*)d_in[7];
  const float* V1 = (const float*)d_in[8];
  const float* c1 = (const float*)d_in[9];
  const float* V2 = (const float*)d_in[10];
  const float* c2 = (const float*)d_in[11];
  const float* V3 = (const float*)d_in[12];
  const float* c3 = (const float*)d_in[13];
  float* out = (float*)d_out;

  bf16* Xbf = (bf16*)d_ws;                         // B*H  (4 MB)
  bf16* Ybf = Xbf + (size_t)BB * HH;               // B*H  (4 MB)
  bf16* W2bf = Ybf + (size_t)BB * HH;              // H*H  (0.5 MB)
  bf16* V2bf = W2bf + (size_t)HH * HH;             // H*H  (0.5 MB)
  bf16* W1bf = V2bf + (size_t)HH * HH;             // 512x64
  bf16* V1bf = W1bf + (size_t)HH * DD;             // 512x64
  bf16* W3bf = V1bf + (size_t)HH * DD;             // 64x512
  bf16* V3bf = W3bf + (size_t)DD * HH;             // 64x512
  f16* W1Th = (f16*)(V3bf + (size_t)DD * HH);      // 64x512 f16
  f16* W2h = W1Th + (size_t)DD * HH;               // H*H f16 (0.5 MB)
  float* Jpart = (float*)(W2h + (size_t)HH * HH);  // 4*B*64 f32 (4 MB)

  cvt_weights<<<dim3(928), 256, 0, stream>>>(W2, V2, W1, V1, W3, V3,
                                             W2bf, V2bf, W1Th, W1bf, V1bf,
                                             W3bf, V3bf, W2h);
  fwd<<<dim3(256, 2), 256, 0, stream>>>(states, W1bf, b1, W2bf, b2, W3bf, b3,
                                        V1bf, c1, V2bf, c2, V3bf, c3,
                                        Xbf, Ybf, out);
  k4_gemm<<<dim3(2048, 4), 256, 0, stream>>>(Xbf, Ybf, W1Th, W2h, W3, Jpart);
  combine<<<dim3(1024), 256, 0, stream>>>(Jpart, states, out);
}

// Round 22
// 314.711 us; speedup vs baseline: 1.0999x; 1.0226x over previous
//
#include <hip/hip_runtime.h>
#include <hip/hip_bf16.h>

#define BB 4096
#define DD 64
#define HH 512

typedef __hip_bfloat16 bf16;
typedef _Float16 f16;
typedef __attribute__((ext_vector_type(8))) short bf16x8;
typedef __attribute__((ext_vector_type(8))) _Float16 f16x8;
typedef __attribute__((ext_vector_type(4))) float f32x4;

__device__ __forceinline__ float bf2f(bf16 x) { return __bfloat162float(x); }
__device__ __forceinline__ float u16tof(unsigned short u) {
  union { unsigned int i; float f; } v; v.i = ((unsigned int)u) << 16; return v.f;
}
#define BC8(p) __builtin_bit_cast(bf16x8, *(const uint4*)(p))
#define BCH8(p) __builtin_bit_cast(f16x8, *(const uint4*)(p))

// ws: Xbf | Ybf (B*H bf16) | W2bf | V2bf (H*H bf16, fwd) |
//     W1bf | V1bf | W3bf | V3bf (fwd) | W1Th (64x512 f16, k4) |
//     W2h (H*H f16, k4) | Jpart (4 x B x 64 f32)   ~13.9 MB
// fwd writes mu -> out[:, :64] and Qd -> out[:, 64:]; combine RMWs out[:, 64:].

// ---------------------------------------------------------------------------
// cvt: [0,256) W2bf; [256,512) V2bf; [512,544) W1Th[d*512+k]=f16(W1[k*64+d]);
//      [544,672) natural bf16 W1,V1,W3,V3; [672,928) W2h = f16(W2).
// ---------------------------------------------------------------------------
__global__ __launch_bounds__(256) void cvt_weights(
    const float* __restrict__ W2, const float* __restrict__ V2,
    const float* __restrict__ W1, const float* __restrict__ V1,
    const float* __restrict__ W3, const float* __restrict__ V3,
    bf16* __restrict__ W2bf, bf16* __restrict__ V2bf, f16* __restrict__ W1Th,
    bf16* __restrict__ W1bf, bf16* __restrict__ V1bf,
    bf16* __restrict__ W3bf, bf16* __restrict__ V3bf, f16* __restrict__ W2h) {
  int blk = blockIdx.x, t = threadIdx.x;
  if (blk < 512) {
    const float* src = (blk < 256) ? W2 : V2;
    bf16* dst = (blk < 256) ? W2bf : V2bf;
    int i = ((blk & 255) * 256 + t) * 4;
    float4 v = *(const float4*)(src + i);
    bf16 o[4] = {__float2bfloat16(v.x), __float2bfloat16(v.y),
                 __float2bfloat16(v.z), __float2bfloat16(v.w)};
    *(uint2*)(dst + i) = *(uint2*)o;
  } else if (blk < 544) {
    int e = (blk - 512) * 1024 + t * 4;
    int d = e >> 9, k0 = e & 511;
    f16 o[4];
#pragma unroll
    for (int j = 0; j < 4; ++j) o[j] = (f16)W1[(size_t)(k0 + j) * 64 + d];
    *(uint2*)(W1Th + e) = *(uint2*)o;
  } else if (blk < 672) {
    int which = (blk - 544) >> 5;
    int local = (blk - 544) & 31;
    const float* src = (which == 0) ? W1 : (which == 1) ? V1 : (which == 2) ? W3 : V3;
    bf16* dst = (which == 0) ? W1bf : (which == 1) ? V1bf : (which == 2) ? W3bf : V3bf;
    int i = (local * 256 + t) * 4;
    float4 v = *(const float4*)(src + i);
    bf16 o[4] = {__float2bfloat16(v.x), __float2bfloat16(v.y),
                 __float2bfloat16(v.z), __float2bfloat16(v.w)};
    *(uint2*)(dst + i) = *(uint2*)o;
  } else {
    int i = ((blk - 672) * 256 + t) * 4;
    float4 v = *(const float4*)(W2 + i);
    f16 o[4] = {(f16)v.x, (f16)v.y, (f16)v.z, (f16)v.w};
    *(uint2*)(W2h + i) = *(uint2*)o;
  }
}

// ---------------------------------------------------------------------------
// fwd v3 (R21 verbatim): 16-row stripes, grid (256, 2), LDS 41.7 KB.
// ---------------------------------------------------------------------------
__global__ __launch_bounds__(256) void fwd(
    const float* __restrict__ states,
    const bf16* __restrict__ W1bf, const float* __restrict__ b1,
    const bf16* __restrict__ W2bf, const float* __restrict__ b2,
    const bf16* __restrict__ W3bf, const float* __restrict__ b3,
    const bf16* __restrict__ V1bf, const float* __restrict__ c1,
    const bf16* __restrict__ V2bf, const float* __restrict__ c2,
    const bf16* __restrict__ V3bf, const float* __restrict__ c3,
    bf16* __restrict__ Xbf, bf16* __restrict__ Ybf, float* __restrict__ out) {
  __shared__ __align__(16) bf16 mus[16 * 72];
  __shared__ __align__(16) bf16 Xres[16 * 520];
  __shared__ __align__(16) bf16 Bs[128 * 72];
  __shared__ __align__(16) bf16 Ych[16 * 136];
  const int bt = blockIdx.x * 16;
  const int path = blockIdx.y;
  const bf16* Wa = path ? V1bf : W1bf;
  const float* ba = path ? c1 : b1;
  const bf16* Wb = path ? V2bf : W2bf;
  const float* bbv = path ? c2 : b2;
  const bf16* Wc = path ? V3bf : W3bf;
  const float* bcv = path ? c3 : b3;
  const int t = threadIdx.x;
  const int lane = t & 63;
  const int w = t >> 6;
  const int c = lane & 15, q = lane >> 4;

  if (t < 128) {
    int row = t >> 3, cg = (t & 7) * 8;
    bf16 o[8];
#pragma unroll
    for (int j = 0; j < 8; j += 4) {
      float4 v = *(const float4*)(states + (size_t)(bt + row) * 128 + cg + j);
      o[j] = __float2bfloat16(v.x); o[j + 1] = __float2bfloat16(v.y);
      o[j + 2] = __float2bfloat16(v.z); o[j + 3] = __float2bfloat16(v.w);
    }
    *(uint4*)(mus + row * 72 + cg) = *(const uint4*)o;
  }
  __syncthreads();

  // L1: X = tanh(mu @ Wa^T + ba), K=64, 4 N-chunks of 128
  for (int nch = 0; nch < 4; ++nch) {
    if (nch) __syncthreads();
#pragma unroll
    for (int i = 0; i < 4; ++i) {
      int g = t + i * 256;
      int row = g >> 3, kb = (g & 7) * 8;
      *(uint4*)(Bs + row * 72 + kb) =
          *(const uint4*)(Wa + (size_t)(nch * 128 + row) * 64 + kb);
    }
    __syncthreads();
    f32x4 acc1[2] = {};
#pragma unroll
    for (int s = 0; s < 2; ++s) {
      bf16x8 af = BC8(mus + c * 72 + s * 32 + q * 8);
#pragma unroll
      for (int nt = 0; nt < 2; ++nt) {
        bf16x8 bfr = BC8(Bs + (w * 32 + nt * 16 + c) * 72 + s * 32 + q * 8);
        acc1[nt] = __builtin_amdgcn_mfma_f32_16x16x32_bf16(af, bfr, acc1[nt], 0, 0, 0);
      }
    }
#pragma unroll
    for (int nt = 0; nt < 2; ++nt) {
      int col = nch * 128 + w * 32 + nt * 16 + c;
      float bias = ba[col];
#pragma unroll
      for (int r = 0; r < 4; ++r) {
        int row = q * 4 + r;
        float x = tanhf(acc1[nt][r] + bias);
        Xres[row * 520 + col] = __float2bfloat16(x);
        if (!path) Xbf[(size_t)(bt + row) * HH + col] = __float2bfloat16(x);
      }
    }
  }
  __syncthreads();

  // L2 + L3-fold over 4 h-chunks of 128
  f32x4 acc3 = {};
  for (int hch = 0; hch < 4; ++hch) {
    f32x4 acc2[2] = {};
    for (int kc = 0; kc < 8; ++kc) {
      __syncthreads();
#pragma unroll
      for (int i = 0; i < 4; ++i) {
        int g = t + i * 256;
        int row = g >> 3, kb = (g & 7) * 8;
        *(uint4*)(Bs + row * 72 + kb) =
            *(const uint4*)(Wb + (size_t)(hch * 128 + row) * HH + kc * 64 + kb);
      }
      __syncthreads();
#pragma unroll
      for (int s = 0; s < 2; ++s) {
        bf16x8 af = BC8(Xres + c * 520 + kc * 64 + s * 32 + q * 8);
#pragma unroll
        for (int nt = 0; nt < 2; ++nt) {
          bf16x8 bfr = BC8(Bs + (w * 32 + nt * 16 + c) * 72 + s * 32 + q * 8);
          acc2[nt] = __builtin_amdgcn_mfma_f32_16x16x32_bf16(af, bfr, acc2[nt], 0, 0, 0);
        }
      }
    }
    __syncthreads();
#pragma unroll
    for (int nt = 0; nt < 2; ++nt) {
      int hl = w * 32 + nt * 16 + c;
      int h = hch * 128 + hl;
      float bias = bbv[h];
#pragma unroll
      for (int r = 0; r < 4; ++r) {
        int row = q * 4 + r;
        float y = tanhf(acc2[nt][r] + bias);
        Ych[row * 136 + hl] = __float2bfloat16(y);
        if (!path) Ybf[(size_t)(bt + row) * HH + h] = __float2bfloat16(y);
      }
    }
    __syncthreads();
#pragma unroll
    for (int s3 = 0; s3 < 4; ++s3) {
      bf16x8 bf3 = BC8(Wc + (size_t)(w * 16 + c) * HH + hch * 128 + s3 * 32 + q * 8);
      bf16x8 af3 = BC8(Ych + c * 136 + s3 * 32 + q * 8);
      acc3 = __builtin_amdgcn_mfma_f32_16x16x32_bf16(af3, bf3, acc3, 0, 0, 0);
    }
  }
  {
    int o = w * 16 + c;
    float bias = bcv[o];
#pragma unroll
    for (int r = 0; r < 4; ++r) {
      int row = q * 4 + r;
      float v = acc3[r] + bias;
      if (path) {
        v = fmaxf(v, 0.0f) + log1pf(expf(-fabsf(v)));
        out[(size_t)(bt + row) * 128 + 64 + o] = v;
      } else {
        out[(size_t)(bt + row) * 128 + o] = v;
      }
    }
  }
}

// ---------------------------------------------------------------------------
// k4 v13: R17's fp16 K-loop VERBATIM, but epilogue arrays (w3s, red) OVERLAID
// onto the dead As/Bs regions post-loop. Static LDS 39.9 KB -> exactly
// 4 blocks/CU, enforced via __launch_bounds__(256, 4). grid (2048, 4).
// ---------------------------------------------------------------------------
__global__ __launch_bounds__(256, 4) void k4_gemm(
    const bf16* __restrict__ Xbf, const bf16* __restrict__ Ybf,
    const f16* __restrict__ W1Th, const f16* __restrict__ W2h,
    const float* __restrict__ W3, float* __restrict__ Jpart) {
  __shared__ __align__(16) f16 smem[2 * 128 * 72];  // 36864 B: As | Bs
  __shared__ __align__(16) f16 d1h[2 * 512];        //  2048 B
  __shared__ __align__(16) float d2f[2 * 128];      //  1024 B
  f16* As = smem;
  f16* Bs = smem + 128 * 72;
  const int bt = blockIdx.x;                       // b-pair index
  const int h0 = blockIdx.y * 128;
  const int t = threadIdx.x;
  const int lane = t & 63;
  const int w = t >> 6, wm = w & 1, wn = w >> 1;
  const int c = lane & 15, q = lane >> 4;

  // stage d1h = f16(1 - h1^2) (2 rows x 512)
#pragma unroll
  for (int i = 0; i < 4; ++i) {
    int e = t + i * 256;
    float x = bf2f(Xbf[(size_t)(bt * 2 + (e >> 9)) * HH + (e & 511)]);
    d1h[e] = (f16)(1.0f - x * x);
  }
  // stage d2f = 1 - h2^2 for this h-tile (2 x 128, f32)
  {
    float y = bf2f(Ybf[(size_t)(bt * 2 + (t >> 7)) * HH + h0 + (t & 127)]);
    d2f[t] = 1.0f - y * y;
  }
  __syncthreads();

  f32x4 acc[4][4] = {};
  for (int kc = 0; kc < 8; ++kc) {
    // build As via packed f16 mul + copy Bs
#pragma unroll
    for (int i = 0; i < 4; ++i) {
      int g = t + i * 256;
      int m = g >> 3, kb = (g & 7) * 8;
      int bb = m >> 6, dl = m & 63;
      f16x8 w1v = BCH8(W1Th + (size_t)dl * HH + kc * 64 + kb);
      f16x8 d1v = BCH8(d1h + bb * 512 + kc * 64 + kb);
      f16x8 av = d1v * w1v;                         // 4x v_pk_mul_f16
      *(uint4*)(As + m * 72 + kb) = __builtin_bit_cast(uint4, av);
      *(uint4*)(Bs + m * 72 + kb) =
          *(const uint4*)(W2h + (size_t)(h0 + m) * HH + kc * 64 + kb);
    }
    __syncthreads();
#pragma unroll
    for (int s = 0; s < 2; ++s) {
      f16x8 af[4], bfr[4];
#pragma unroll
      for (int mt = 0; mt < 4; ++mt)
        af[mt] = BCH8(As + (wm * 64 + mt * 16 + c) * 72 + s * 32 + q * 8);
#pragma unroll
      for (int nt = 0; nt < 4; ++nt)
        bfr[nt] = BCH8(Bs + (wn * 64 + nt * 16 + c) * 72 + s * 32 + q * 8);
#pragma unroll
      for (int mt = 0; mt < 4; ++mt)
#pragma unroll
        for (int nt = 0; nt < 4; ++nt)
          acc[mt][nt] = __builtin_amdgcn_mfma_f32_16x16x32_f16(
              af[mt], bfr[nt], acc[mt][nt], 0, 0, 0);
    }
    __syncthreads();
  }

  // ---- epilogue: overlay w3s into As region (dead), red into Bs region ----
  f16* w3s = As;                       // 64 x 136 f16 = 17408 B <= 18432
  float* red = (float*)Bs;             // 256 f32 = 1024 B
  // stage w3s = f16(W3[dl, h0+hl]) (64 x 128, stride 136)
#pragma unroll
  for (int i = 0; i < 8; ++i) {
    int e = (t + i * 256) * 4;
    int dl = e >> 7, hl = e & 127;
    float4 v = *(const float4*)(W3 + (size_t)dl * HH + h0 + hl);
    f16 o[4] = {(f16)v.x, (f16)v.y, (f16)v.z, (f16)v.w};
    *(uint2*)(w3s + dl * 136 + hl) = *(uint2*)o;
  }
  __syncthreads();

  // v[m] = sum_n C[m,n] * d2f[bb,n] * w3s[dl,n]; reduce over c lanes
#pragma unroll
  for (int mt = 0; mt < 4; ++mt) {
#pragma unroll
    for (int r = 0; r < 4; ++r) {
      int m = wm * 64 + mt * 16 + q * 4 + r;
      int bb = m >> 6, dl = m & 63;
      float v = 0.f;
#pragma unroll
      for (int nt = 0; nt < 4; ++nt) {
        int n = wn * 64 + nt * 16 + c;
        v += acc[mt][nt][r] * d2f[bb * 128 + n] * (float)w3s[dl * 136 + n];
      }
      v += __shfl_xor(v, 1);
      v += __shfl_xor(v, 2);
      v += __shfl_xor(v, 4);
      v += __shfl_xor(v, 8);
      if (c == 0) red[wn * 128 + m] = v;
    }
  }
  __syncthreads();
  if (t < 128) {
    float J = red[t] + red[128 + t];
    Jpart[(size_t)blockIdx.y * (BB * 64) + (size_t)bt * 128 + t] = J;
  }
}

// ---------------------------------------------------------------------------
// combine: out[b,64+d] = 2*(sum of 4 Jpart planes)*sigma + out (Qd stash)
// ---------------------------------------------------------------------------
__global__ __launch_bounds__(256) void combine(
    const float* __restrict__ Jpart, const float* __restrict__ states,
    float* __restrict__ out) {
  int idx = blockIdx.x * 256 + threadIdx.x;
  int b = idx >> 6, d = idx & 63;
  const int plane = BB * 64;
  float J = Jpart[idx] + Jpart[plane + idx] + Jpart[2 * plane + idx] +
            Jpart[3 * plane + idx];
  float sig = states[(size_t)b * 128 + 64 + d];
  float qd = out[(size_t)b * 128 + 64 + d];
  out[(size_t)b * 128 + 64 + d] = 2.0f * J * sig + qd;
}

extern "C" void kernel_launch(void* const* d_in, const int* in_sizes, int n_in,
                              void* d_out, int out_size, void* d_ws, size_t ws_size,
                              hipStream_t stream) {
  // inputs: 0:t 1:states 2:W1 3:b1 4:W2 5:b2 6:W3 7:b3 8:V1 9:c1 10:V2 11:c2 12:V3 13:c3
  const float* states = (const float*)d_in[1];
  const float* W1 = (const float*)d_in[2];
  const float* b1 = (const float*)d_in[3];
  const float* W2 = (const float*)d_in[4];
  const float* b2 = (const float*)d_in[5];
  const float* W3 = (const float*)d_in[6];
  const float* b3 = (const float*)d_in[7];
  const float* V1 = (const float*)d_in[8];
  const float* c1 = (const float*)d_in[9];
  const float* V2 = (const float*)d_in[10];
  const float* c2 = (const float*)d_in[11];
  const float* V3 = (const float*)d_in[12];
  const float* c3 = (const float*)d_in[13];
  float* out = (float*)d_out;

  bf16* Xbf = (bf16*)d_ws;                         // B*H  (4 MB)
  bf16* Ybf = Xbf + (size_t)BB * HH;               // B*H  (4 MB)
  bf16* W2bf = Ybf + (size_t)BB * HH;              // H*H  (0.5 MB)
  bf16* V2bf = W2bf + (size_t)HH * HH;             // H*H  (0.5 MB)
  bf16* W1bf = V2bf + (size_t)HH * HH;             // 512x64
  bf16* V1bf = W1bf + (size_t)HH * DD;             // 512x64
  bf16* W3bf = V1bf + (size_t)HH * DD;             // 64x512
  bf16* V3bf = W3bf + (size_t)DD * HH;             // 64x512
  f16* W1Th = (f16*)(V3bf + (size_t)DD * HH);      // 64x512 f16
  f16* W2h = W1Th + (size_t)DD * HH;               // H*H f16 (0.5 MB)
  float* Jpart = (float*)(W2h + (size_t)HH * HH);  // 4*B*64 f32 (4 MB)

  cvt_weights<<<dim3(928), 256, 0, stream>>>(W2, V2, W1, V1, W3, V3,
                                             W2bf, V2bf, W1Th, W1bf, V1bf,
                                             W3bf, V3bf, W2h);
  fwd<<<dim3(256, 2), 256, 0, stream>>>(states, W1bf, b1, W2bf, b2, W3bf, b3,
                                        V1bf, c1, V2bf, c2, V3bf, c3,
                                        Xbf, Ybf, out);
  k4_gemm<<<dim3(2048, 4), 256, 0, stream>>>(Xbf, Ybf, W1Th, W2h, W3, Jpart);
  combine<<<dim3(1024), 256, 0, stream>>>(Jpart, states, out);
}